// Round 1
// 299.478 us; speedup vs baseline: 1.0077x; 1.0077x over previous
//
#include <hip/hip_runtime.h>
#include <hip/hip_bf16.h>

// Implicit-GEMM conv: M = 32*54*54 = 93312, N = 256 (co), K = 9*256 = 2304.
// R4: 8-phase-style pipelined K-loop (T3+T4+T5 from the technique catalog):
//   - BM=128 x BN=256 (full-N tile column: A read exactly once, B L2-resident)
//   - 512 threads / 8 waves (2M x 4N), per-wave 64x64, 16 MFMA per K-tile
//   - BK=32, 4-deep LDS ring (96 KB), glds staging issued 3 tiles ahead
//   - counted s_waitcnt vmcnt(6) + single raw s_barrier per tile (no drain)
//   - s_setprio(1) around the MFMA cluster
// Staging swizzle (pre-swizzled global source + swizzled ds_read) unchanged.

typedef __bf16 bf16x8 __attribute__((ext_vector_type(8)));
typedef float f32x4 __attribute__((ext_vector_type(4)));

#define GLOBAL_AS __attribute__((address_space(1)))
#define LDS_AS __attribute__((address_space(3)))

static __device__ __forceinline__ void glds16(const void* g, void* l) {
    __builtin_amdgcn_global_load_lds((const GLOBAL_AS unsigned int*)g,
                                     (LDS_AS unsigned int*)l, 16, 0, 0);
}

static __device__ __forceinline__ unsigned short f2bf(float f) {
    unsigned int u = __float_as_uint(f);
    unsigned int r = u + 0x7FFFu + ((u >> 16) & 1u);  // RNE
    return (unsigned short)(r >> 16);
}

// ---- combined conversion: blocks [0,12544) convert x, [12544,12800) convert w ----
__global__ void cvt_xw(const float* __restrict__ x, unsigned short* __restrict__ xb,
                       const float* __restrict__ w, unsigned short* __restrict__ wt) {
    const int NXB = 32 * 56 * 56 * 256 / (256 * 8);  // 12544
    if (blockIdx.x < NXB) {
        int i = (blockIdx.x * 256 + threadIdx.x) * 8;
        const float4* p = (const float4*)(x + i);
        float4 a = p[0], b = p[1];
        uint4 v;
        v.x = (unsigned)f2bf(a.x) | ((unsigned)f2bf(a.y) << 16);
        v.y = (unsigned)f2bf(a.z) | ((unsigned)f2bf(a.w) << 16);
        v.z = (unsigned)f2bf(b.x) | ((unsigned)f2bf(b.y) << 16);
        v.w = (unsigned)f2bf(b.z) | ((unsigned)f2bf(b.w) << 16);
        *(uint4*)(xb + i) = v;
    } else {
        int co = blockIdx.x - NXB;
        int ci = threadIdx.x;
        const float* src = w + co * 2304 + ci * 9;
        unsigned short* dst = wt + co * 2304 + ci;
#pragma unroll
        for (int khw = 0; khw < 9; ++khw) {
            float v = src[khw];
            v = (fabsf(v) < 0.01f) ? 0.0f : v;
            dst[khw * 256] = f2bf(v);
        }
    }
}

// LDS swizzle: row's global k-chunk g (8 bf16 = 16B) lives at slot g ^ key(row mod 16).
static __device__ __forceinline__ int swz_key(int row16) {
    return (row16 & 3) ^ ((row16 >> 2) & 3);
}

// ---- GEMM: Out[m][co] = sum_k A[m][k]*Wt[co][k] + bias[co] ----
__global__ __launch_bounds__(512, 2) void conv_gemm(
    const unsigned short* __restrict__ Xb,   // bf16 bits [32*56*56*256]
    const unsigned short* __restrict__ Wt,   // bf16 bits [256][2304]
    const float* __restrict__ bias,          // [256]
    float* __restrict__ Out)                 // [93312][256]
{
    // 4-deep ring: per K-tile buffer A 128x32 (8KB) + B 256x32 (16KB) -> 96KB total
    __shared__ __align__(16) unsigned short As[4][128 * 32];
    __shared__ __align__(16) unsigned short Bs[4][256 * 32];

    const int tid  = threadIdx.x;            // 0..511
    const int lane = tid & 63;
    const int wave = tid >> 6;               // 0..7

    const int m0 = blockIdx.x * 128;         // 729 blocks, co0 = 0 (BN = full 256)

    // ---- staging source addresses (pre-swizzled global chunk) ----
    // A: slot tid -> row tid>>2 (0..127), LDS chunk tid&3 holds global chunk (tid&3)^key
    const int arow = tid >> 2;
    const int ach  = (tid & 3) ^ swz_key(arow & 15);
    int am = m0 + arow;
    int an = am / 2916;
    int arem = am - an * 2916;
    int aoh = arem / 54;
    int aow = arem - aoh * 54;
    const unsigned short* a_base =
        Xb + (((an * 56 + aoh) * 56 + aow) << 8) + ach * 8;   // kh=kw=0

    // B: two rounds of 512 slots; slot s -> co s>>2, chunk s&3 (swizzled)
    const int s1 = 512 + tid;
    const int br0 = tid >> 2, br1 = s1 >> 2;
    const unsigned short* b_base0 =
        Wt + br0 * 2304 + (((tid & 3) ^ swz_key(br0 & 15)) << 3);
    const unsigned short* b_base1 =
        Wt + br1 * 2304 + (((s1 & 3) ^ swz_key(br1 & 15)) << 3);

    // ---- fragment read coordinates ----
    const int fm = lane & 15;                // A-row / B-row within 16
    const int fq = lane >> 4;                // k-chunk index (0..3)
    const int wm = (wave >> 2) * 64;         // 2 M-halves
    const int wn = (wave & 3) * 64;          // 4 N-quarters
    const int slot8 = (fq ^ swz_key(fm)) * 8;

    f32x4 acc[4][4];
#pragma unroll
    for (int i = 0; i < 4; ++i)
#pragma unroll
        for (int j = 0; j < 4; ++j)
            acc[i][j] = (f32x4){0.f, 0.f, 0.f, 0.f};

    // ---- prologue: stage tiles 0,1,2 into ring slots 0,1,2 (9 glds in flight) ----
    // tiles 0..2 are all kh=kw=0, k-offset = t*32 elements
#pragma unroll
    for (int tp = 0; tp < 3; ++tp) {
        glds16(a_base + tp * 32, &As[tp][wave * 512]);
        glds16(b_base0 + tp * 32, &Bs[tp][wave * 512]);
        glds16(b_base1 + tp * 32, &Bs[tp][4096 + wave * 512]);
    }
    // retire tile0's 3 loads (keep 6 in flight), then sync
    asm volatile("s_waitcnt vmcnt(6)\n\ts_barrier" ::: "memory");

    // ---- main loop: 72 K-tiles, one 16-MFMA phase each ----
#pragma unroll 1
    for (int t = 0; t < 72; ++t) {
        const int b = t & 3;
        const unsigned short* Ab = As[b];
        const unsigned short* Bb = Bs[b];
        bf16x8 af[4], bfr[4];
#pragma unroll
        for (int mi = 0; mi < 4; ++mi)
            af[mi] = *(const bf16x8*)&Ab[(wm + mi * 16 + fm) * 32 + slot8];
#pragma unroll
        for (int ni = 0; ni < 4; ++ni)
            bfr[ni] = *(const bf16x8*)&Bb[(wn + ni * 16 + fm) * 32 + slot8];

        // issue stage of tile t+3 into ring slot (t+3)&3; that buffer's previous
        // contents (tile t-1) finished all LDS reads before the t-1 trailing
        // barrier, so a single barrier per tile is race-free.
        const int tn = t + 3;
        if (tn < 72) {
            const int bn = tn & 3;
            const int khw = tn >> 3;
            const int kh = (khw * 11) >> 5;          // khw/3 for 0..8
            const int kw = khw - kh * 3;
            const int aoff = ((kh * 56 + kw) << 8) + (tn & 7) * 32;
            const int boff = tn * 32;
            glds16(a_base + aoff, &As[bn][wave * 512]);
            glds16(b_base0 + boff, &Bs[bn][wave * 512]);
            glds16(b_base1 + boff, &Bs[bn][4096 + wave * 512]);
        }

        __builtin_amdgcn_s_setprio(1);
#pragma unroll
        for (int mi = 0; mi < 4; ++mi)
#pragma unroll
            for (int ni = 0; ni < 4; ++ni)
                acc[mi][ni] = __builtin_amdgcn_mfma_f32_16x16x32_bf16(
                    af[mi], bfr[ni], acc[mi][ni], 0, 0, 0);
        __builtin_amdgcn_s_setprio(0);

        // counted drain: 9 loads outstanding (t+1,t+2,t+3) -> retire t+1's 3.
        // Tail (t>=69): fewer groups in flight, must drain fully.
        if (t < 69) asm volatile("s_waitcnt vmcnt(6)\n\ts_barrier" ::: "memory");
        else        asm volatile("s_waitcnt vmcnt(0)\n\ts_barrier" ::: "memory");
    }

    // ---- epilogue: D col = lane&15 (co), row = (lane>>4)*4 + reg (m); fuse bias ----
    float bv[4];
#pragma unroll
    for (int ni = 0; ni < 4; ++ni) bv[ni] = bias[wn + ni * 16 + fm];
#pragma unroll
    for (int mi = 0; mi < 4; ++mi) {
#pragma unroll
        for (int reg = 0; reg < 4; ++reg) {
            int m = m0 + wm + mi * 16 + fq * 4 + reg;
            float* orow = Out + m * 256 + wn + fm;
#pragma unroll
            for (int ni = 0; ni < 4; ++ni)
                orow[ni * 16] = acc[mi][ni][reg] + bv[ni];
        }
    }
}

extern "C" void kernel_launch(void* const* d_in, const int* in_sizes, int n_in,
                              void* d_out, int out_size, void* d_ws, size_t ws_size,
                              hipStream_t stream) {
    const float* x    = (const float*)d_in[0];  // (32,56,56,256) fp32
    const float* w    = (const float*)d_in[1];  // (256,256,3,3) fp32
    const float* bias = (const float*)d_in[2];  // (256,) fp32
    float* out = (float*)d_out;                 // (32,54,54,256) fp32

    const int NX = 32 * 56 * 56 * 256;  // 25,690,112
    unsigned short* xb = (unsigned short*)d_ws;
    unsigned short* wt = xb + NX;

    cvt_xw<<<NX / (256 * 8) + 256, 256, 0, stream>>>(x, xb, w, wt);
    conv_gemm<<<729, 512, 0, stream>>>(xb, wt, bias, out);
}